// Round 2
// baseline (5148.664 us; speedup 1.0000x reference)
//
#include <hip/hip_runtime.h>
#include <hip/hip_bf16.h>

typedef __hip_bfloat16 bf16;

// Runtime dtype flag: 1 = float inputs are bf16, 0 = fp32.
// Probed from ln1_g (all ones): bf16 pair = 0x3F803F80, fp32 = 0x3F800000.
__global__ void probe_kernel(const void* __restrict__ ones_vec, int* __restrict__ flag) {
  unsigned u = *(const unsigned*)ones_vec;
  *flag = (u == 0x3F803F80u) ? 1 : 0;
}

__device__ __forceinline__ float ldw(const void* p, size_t i, int isbf) {
  return isbf ? __bfloat162float(((const bf16*)p)[i]) : ((const float*)p)[i];
}

// ---------------------------------------------------------------- build x0
__global__ void build_x0_kernel(const void* __restrict__ ent_emb, const void* __restrict__ rel_emb,
                                const void* __restrict__ pos_emb, const int* __restrict__ rel_idx,
                                const int* __restrict__ ent_idx, float* __restrict__ x0,
                                const int* __restrict__ dflag) {
  const int isbf = *dflag;
  int idx = blockIdx.x * 256 + threadIdx.x;
  if (idx >= 512 * 4 * 400) return;
  int d = idx % 400;
  int l = (idx / 400) % 4;
  int b = idx / 1600;
  float v;
  if (l == 0) v = ldw(rel_emb, (size_t)rel_idx[b] * 400 + d, isbf);
  else        v = ldw(ent_emb, (size_t)ent_idx[b * 3 + l - 1] * 400 + d, isbf);
  x0[idx] = v + ldw(pos_emb, l * 400 + d, isbf);
}

// ---------------------------------------------------------------- generic GEMM
// Y[m,n] = sum_k X[m*lda+k] * W[n*K+k] + bias[n]; X fp32 (workspace), W/bias per-flag.
// M % 64 == 0, K % 16 == 0. OUTV: store via flag dtype (final output), else fp32.
template<bool RELU, bool NSWAP, bool OUTV>
__global__ __launch_bounds__(256) void gemm_kernel(
    const float* __restrict__ X, int lda,
    const void* __restrict__ W, const void* __restrict__ bvec,
    void* __restrict__ Y, long long ldc,
    int M, int N, int K, const int* __restrict__ dflag) {
  const int isbf = *dflag;
  int ntile = NSWAP ? blockIdx.y : blockIdx.x;
  int mtile = NSWAP ? blockIdx.x : blockIdx.y;
  int n0 = ntile * 64, m0 = mtile * 64;
  __shared__ float Xs[16][64];
  __shared__ float Ws[16][64];
  int tid = threadIdx.x;
  int tx = tid & 15, ty = tid >> 4;
  int lr = tid >> 2;            // 0..63 row within tile
  int lc = (tid & 3) << 2;      // 0,4,8,12 col within K-tile
  float acc[4][4] = {};
  const float* xbase = X + (size_t)(m0 + lr) * lda + lc;
  int wn = n0 + lr;
  bool wvalid = wn < N;
  size_t wrow = (size_t)(wvalid ? wn : 0) * K + lc;
  for (int k0 = 0; k0 < K; k0 += 16) {
#pragma unroll
    for (int j = 0; j < 4; ++j) Xs[lc + j][lr] = xbase[k0 + j];
#pragma unroll
    for (int j = 0; j < 4; ++j) Ws[lc + j][lr] = wvalid ? ldw(W, wrow + k0 + j, isbf) : 0.f;
    __syncthreads();
#pragma unroll
    for (int kk = 0; kk < 16; ++kk) {
      float xv[4], wv[4];
#pragma unroll
      for (int a = 0; a < 4; ++a) xv[a] = Xs[kk][ty * 4 + a];
#pragma unroll
      for (int b = 0; b < 4; ++b) wv[b] = Ws[kk][tx * 4 + b];
#pragma unroll
      for (int a = 0; a < 4; ++a)
#pragma unroll
        for (int b = 0; b < 4; ++b)
          acc[a][b] = fmaf(xv[a], wv[b], acc[a][b]);
    }
    __syncthreads();
  }
#pragma unroll
  for (int a = 0; a < 4; ++a) {
    int m = m0 + ty * 4 + a;
#pragma unroll
    for (int b = 0; b < 4; ++b) {
      int n = n0 + tx * 4 + b;
      if (n < N) {
        float v = acc[a][b] + ldw(bvec, n, isbf);
        if (RELU) v = fmaxf(v, 0.f);
        size_t off = (size_t)m * ldc + n;
        if (OUTV) {
          if (isbf) ((bf16*)Y)[off] = __float2bfloat16(v);
          else      ((float*)Y)[off] = v;
        } else {
          ((float*)Y)[off] = v;
        }
      }
    }
  }
}

// ---------------------------------------------------------------- attention scores + softmax
__device__ __forceinline__ float wave_sum(float v) {
#pragma unroll
  for (int o = 32; o > 0; o >>= 1) v += __shfl_xor(v, o);
  return v;
}

__global__ void score_kernel(const float* __restrict__ q, const float* __restrict__ k,
                             float* __restrict__ att) {
  int bh = blockIdx.x;            // b*4 + h
  int h = bh & 3, b = bh >> 2;
  int lane = threadIdx.x;
  float s[4][4];
#pragma unroll
  for (int l = 0; l < 4; ++l) {
    const float* qp = q + (size_t)(b * 4 + l) * 1600 + h * 400;
#pragma unroll
    for (int m = 0; m < 4; ++m) {
      const float* kp = k + (size_t)(b * 4 + m) * 1600 + h * 400;
      float p = 0.f;
      for (int d = lane; d < 400; d += 64) p += qp[d] * kp[d];
      s[l][m] = wave_sum(p) * 0.05f;   // 1/sqrt(400)
    }
  }
  if (lane < 16) {
    int l = lane >> 2, m = lane & 3;
    float mx = fmaxf(fmaxf(s[l][0], s[l][1]), fmaxf(s[l][2], s[l][3]));
    float e0 = expf(s[l][0] - mx), e1 = expf(s[l][1] - mx);
    float e2 = expf(s[l][2] - mx), e3 = expf(s[l][3] - mx);
    float inv = 1.f / (e0 + e1 + e2 + e3);
    float ev = (m == 0) ? e0 : (m == 1) ? e1 : (m == 2) ? e2 : e3;
    att[(size_t)bh * 16 + l * 4 + m] = ev * inv;
  }
}

// o[b,l,h,d] = sum_m att[b,h,l,m] * v[b,m,h,d]
__global__ void attn_apply_kernel(const float* __restrict__ att, const float* __restrict__ v,
                                  float* __restrict__ o) {
  int idx = blockIdx.x * 256 + threadIdx.x;
  if (idx >= 2048 * 1600) return;
  int col = idx % 1600;       // h*400 + d
  int row = idx / 1600;       // b*4 + l
  int b = row >> 2, l = row & 3, h = col / 400;
  const float* ap = att + ((size_t)b * 4 + h) * 16 + l * 4;
  float acc = 0.f;
#pragma unroll
  for (int m = 0; m < 4; ++m) acc += ap[m] * v[(size_t)(b * 4 + m) * 1600 + col];
  o[idx] = acc;
}

// ---------------------------------------------------------------- rowwise LN(A + Bv), len 400
__global__ __launch_bounds__(128) void ln_kernel(const float* __restrict__ A, const float* __restrict__ Bv,
                                                 const void* __restrict__ g, const void* __restrict__ beta,
                                                 float* __restrict__ out, const int* __restrict__ dflag) {
  const int isbf = *dflag;
  int row = blockIdx.x;
  int tid = threadIdx.x;
  const float* a = A + (size_t)row * 400;
  const float* bb = Bv + (size_t)row * 400;
  float vals[4] = {};
  float s = 0.f, q = 0.f;
#pragma unroll
  for (int j = 0; j < 4; ++j) {
    int d = tid + j * 128;
    if (d < 400) { float x = a[d] + bb[d]; vals[j] = x; s += x; q += x * x; }
  }
  __shared__ float rs[128], rq[128];
  rs[tid] = s; rq[tid] = q;
  __syncthreads();
  for (int off = 64; off > 0; off >>= 1) {
    if (tid < off) { rs[tid] += rs[tid + off]; rq[tid] += rq[tid + off]; }
    __syncthreads();
  }
  float mean = rs[0] * (1.f / 400.f);
  float var = rq[0] * (1.f / 400.f) - mean * mean;
  float rstd = rsqrtf(var + 1e-5f);
  float* op = out + (size_t)row * 400;
#pragma unroll
  for (int j = 0; j < 4; ++j) {
    int d = tid + j * 128;
    if (d < 400) op[d] = (vals[j] - mean) * rstd * ldw(g, d, isbf) + ldw(beta, d, isbf);
  }
}

// ---------------------------------------------------------------- global mean/rstd over a strided 2-D slab
__global__ __launch_bounds__(1024) void stat_kernel(const float* __restrict__ base, int slice_stride,
                                                    int row_stride, int len, int nrows,
                                                    float* __restrict__ out) {
  const float* p = base + (size_t)blockIdx.x * slice_stride;
  int tid = threadIdx.x;
  int total = nrows * len;
  float s = 0.f, q = 0.f;
  for (int t = tid; t < total; t += 1024) {
    float x = p[(size_t)(t / len) * row_stride + (t % len)];
    s += x; q += x * x;
  }
  __shared__ float rs[1024], rq[1024];
  rs[tid] = s; rq[tid] = q;
  __syncthreads();
  for (int off = 512; off > 0; off >>= 1) {
    if (tid < off) { rs[tid] += rs[tid + off]; rq[tid] += rq[tid + off]; }
    __syncthreads();
  }
  if (tid == 0) {
    float mean = rs[0] / (float)total;
    float var = rq[0] / (float)total - mean * mean;
    out[2 * blockIdx.x] = mean;
    out[2 * blockIdx.x + 1] = rsqrtf(var + 1e-5f);
  }
}

// ---------------------------------------------------------------- y[b, p*400+d] = f[b,p] * xn(e[b,d])
__global__ void build_y_kernel(const float* __restrict__ e /* row stride 1600 */,
                               const float* __restrict__ f, const float* __restrict__ st,
                               const void* __restrict__ pg, const void* __restrict__ pb,
                               float* __restrict__ y, const int* __restrict__ dflag) {
  const int isbf = *dflag;
  int idx = blockIdx.x * 256 + threadIdx.x;
  if (idx >= 512 * 6400) return;
  int d = idx % 400;
  int p = (idx / 400) % 16;
  int b = idx / 6400;
  float m = st[0], rstd = st[1];
  float xn = (e[(size_t)b * 1600 + d] - m) * rstd * ldw(pg, 0, isbf) + ldw(pb, 0, isbf);
  y[idx] = f[b * 16 + p] * xn;
}

// ---------------------------------------------------------------- conv (bkj,bij->bki) + pairwise maxpool
__global__ void convpool_kernel(const float* __restrict__ kern, const float* __restrict__ ef,
                                const float* __restrict__ st, const void* __restrict__ bg_,
                                const void* __restrict__ bb_, float* __restrict__ pooled,
                                const int* __restrict__ dflag) {
  const int isbf = *dflag;
  int idx = blockIdx.x * 256 + threadIdx.x;
  if (idx >= 512 * 32 * 200) return;
  int i2 = idx % 200;
  int k = (idx / 200) % 32;
  int b = idx / 6400;
  float m = st[0], rstd = st[1];
  float bg = ldw(bg_, 0, isbf), bb = ldw(bb_, 0, isbf);
  const float* kp = kern + (size_t)b * 96 + k * 3;
  float k0 = kp[0], k1 = kp[1], k2 = kp[2];
  const float* e = ef + (size_t)b * 1200 + i2 * 6;  // xr[b,0,i,j] = ef_flat[b*1200 + i*3 + j]
  float c0 = k0 * ((e[0] - m) * rstd * bg + bb) + k1 * ((e[1] - m) * rstd * bg + bb) + k2 * ((e[2] - m) * rstd * bg + bb);
  float c1 = k0 * ((e[3] - m) * rstd * bg + bb) + k1 * ((e[4] - m) * rstd * bg + bb) + k2 * ((e[5] - m) * rstd * bg + bb);
  pooled[idx] = fmaxf(c0, c1);
}

// ---------------------------------------------------------------- launch
extern "C" void kernel_launch(void* const* d_in, const int* in_sizes, int n_in,
                              void* d_out, int out_size, void* d_ws, size_t ws_size,
                              hipStream_t stream) {
  const void* ent_emb    = d_in[0];
  const void* rel_emb    = d_in[1];
  const void* pos_emb    = d_in[2];
  const void* relposw_w  = d_in[3];
  const void* relposw_b  = d_in[4];
  const void* relposinv_w= d_in[5];
  const void* relposinv_b= d_in[6];
  const void* relw4_w    = d_in[7];
  const void* relw4_b    = d_in[8];
  const void* q_w        = d_in[9];
  const void* q_b        = d_in[10];
  const void* k_w        = d_in[11];
  const void* k_b        = d_in[12];
  const void* v_w        = d_in[13];
  const void* v_b        = d_in[14];
  const void* fca_w      = d_in[15];
  const void* fca_b      = d_in[16];
  const void* ln1_g      = d_in[17];
  const void* ln1_b      = d_in[18];
  const void* ln2_g      = d_in[19];
  const void* ln2_b      = d_in[20];
  const void* w1_w       = d_in[21];
  const void* w1_b       = d_in[22];
  const void* w2_w       = d_in[23];
  const void* w2_b       = d_in[24];
  const void* fc_w       = d_in[25];
  const void* fc_b       = d_in[26];
  const void* posbn_g    = d_in[27];
  const void* posbn_b    = d_in[28];
  const void* bn_g       = d_in[29];
  const void* bn_b       = d_in[30];
  const void* bias       = d_in[31];
  const int*  rel_idx    = (const int*)d_in[32];
  const int*  ent_idx    = (const int*)d_in[33];
  float* ws = (float*)d_ws;

  // arena (floats), total 8,282,145 floats = 33.1 MB
  float* x0   = ws;                 // 819,200 (2048x400): x0 -> (dead) -> x2
  float* B    = ws + 819200;        // 3,276,800: q -> v -> x1(2048x400 prefix) -> ybuf -> pooled
  float* C    = ws + 4096000;       // 3,276,800: k -> o -> ffn1(2048x800 prefix) -> small tail use
  float* fbuf = ws + 7372800;       //     8,192 (512x16)
  float* kern = ws + 7380992;       //    49,152 (512x96)
  float* ef   = ws + 7430144;       //   614,400 (512x3x400)
  float* hbuf = ws + 8044544;       //   204,800 (512x400)
  float* scal = ws + 8249344;       //        32
  float* att  = ws + 8249376;       //    32,768 (512x4x4x4)
  int*  dflag = (int*)(ws + 8282144);

  dim3 blk(256);

  probe_kernel<<<1, 1, 0, stream>>>(ln1_g, dflag);

  // x0 = gather + pos
  build_x0_kernel<<<3200, blk, 0, stream>>>(ent_emb, rel_emb, pos_emb, rel_idx, ent_idx, x0, dflag);

  // q -> B, k -> C
  {
    dim3 grid(25, 32);
    gemm_kernel<false, false, false><<<grid, blk, 0, stream>>>(x0, 400, q_w, q_b, B, 1600, 2048, 1600, 400, dflag);
    gemm_kernel<false, false, false><<<grid, blk, 0, stream>>>(x0, 400, k_w, k_b, C, 1600, 2048, 1600, 400, dflag);
  }
  score_kernel<<<2048, 64, 0, stream>>>(B, C, att);

  // v -> B (q dead), o -> C (k dead)
  {
    dim3 grid(25, 32);
    gemm_kernel<false, false, false><<<grid, blk, 0, stream>>>(x0, 400, v_w, v_b, B, 1600, 2048, 1600, 400, dflag);
  }
  attn_apply_kernel<<<12800, blk, 0, stream>>>(att, B, C);

  // x1 = LN(x0 + o @ fca^T) -> B[0..819200)
  {
    dim3 grid(7, 32);
    gemm_kernel<false, false, false><<<grid, blk, 0, stream>>>(C, 1600, fca_w, fca_b, B, 400, 2048, 400, 1600, dflag);
  }
  ln_kernel<<<2048, 128, 0, stream>>>(x0, B, ln1_g, ln1_b, B, dflag);

  // FFN: ffn1 -> C, ffn2 -> x0 (x0 dead after ln1), ln2 -> x0 (x2)
  {
    dim3 grid(13, 32);
    gemm_kernel<true, false, false><<<grid, blk, 0, stream>>>(B, 400, w1_w, w1_b, C, 800, 2048, 800, 400, dflag);
  }
  {
    dim3 grid(7, 32);
    gemm_kernel<false, false, false><<<grid, blk, 0, stream>>>(C, 800, w2_w, w2_b, x0, 400, 2048, 400, 800, dflag);
  }
  ln_kernel<<<2048, 128, 0, stream>>>(B, x0, ln2_g, ln2_b, x0, dflag);
  float* x2 = x0;

  // f = r @ relposw^T ; kern = r @ relw4^T   (r = x2[:,0,:], row stride 1600)
  {
    dim3 grid(1, 8);
    gemm_kernel<false, false, false><<<grid, blk, 0, stream>>>(x2, 1600, relposw_w, relposw_b, fbuf, 16, 512, 16, 400, dflag);
  }
  {
    dim3 grid(2, 8);
    gemm_kernel<false, false, false><<<grid, blk, 0, stream>>>(x2, 1600, relw4_w, relw4_b, kern, 96, 512, 96, 400, dflag);
  }

  // global stats of x2[:, i+1, :] -> scal[0..5]
  stat_kernel<<<3, 1024, 0, stream>>>(x2 + 400, 400, 1600, 400, 512, scal);

  // ra_pos: y = f ⊗ xn -> B (3.27M, free); ef[:, i, :] = y @ relposinv^T
  for (int i = 0; i < 3; ++i) {
    build_y_kernel<<<12800, blk, 0, stream>>>(x2 + (i + 1) * 400, fbuf, scal + 2 * i, posbn_g, posbn_b, B, dflag);
    dim3 grid(7, 8);
    gemm_kernel<false, false, false><<<grid, blk, 0, stream>>>(B, 6400, relposinv_w, relposinv_b, ef + i * 400, 1200, 512, 400, 6400, dflag);
  }

  // global stats of ef (as xr) -> scal[6..7]
  stat_kernel<<<1, 1024, 0, stream>>>(ef, 0, 1200, 1200, 512, scal + 6);

  // conv + maxpool -> B (pooled, 512x6400)
  convpool_kernel<<<12800, blk, 0, stream>>>(kern, ef, scal + 6, bn_g, bn_b, B, dflag);

  // h = relu(pooled @ fc^T) -> hbuf
  {
    dim3 grid(7, 8);
    gemm_kernel<true, false, false><<<grid, blk, 0, stream>>>(B, 6400, fc_w, fc_b, hbuf, 400, 512, 400, 6400, dflag);
  }

  // out = h @ ent_emb^T + bias  (M=512, N=200000), NSWAP for ent_emb tile reuse across adjacent blocks
  {
    dim3 grid(8, 3125);
    gemm_kernel<false, true, true><<<grid, blk, 0, stream>>>(hbuf, 400, ent_emb, bias, d_out, 200000, 512, 200000, 400, dflag);
  }
}

// Round 3
// 1521.262 us; speedup vs baseline: 3.3845x; 3.3845x over previous
//
#include <hip/hip_runtime.h>

typedef unsigned short u16;
typedef __attribute__((ext_vector_type(8))) short s8v;    // 8 bf16 = 4 VGPRs (MFMA A/B frag)
typedef __attribute__((ext_vector_type(4))) float f4v;    // MFMA C/D frag
typedef __attribute__((ext_vector_type(4))) unsigned int u32x4;

typedef const __attribute__((address_space(1))) unsigned gas_u32;
typedef __attribute__((address_space(3))) unsigned las_u32;

__device__ __forceinline__ float bf2f(u16 u) { return __uint_as_float(((unsigned)u) << 16); }
__device__ __forceinline__ u16 f2bf(float x) {
  unsigned b = __float_as_uint(x);
  return (u16)((b + 0x7FFFu + ((b >> 16) & 1u)) >> 16);
}

// ---------------------------------------------------------------- weight fp32 -> bf16 (K-padded)
__global__ void convert_w_kernel(const float* __restrict__ src, u16* __restrict__ dst,
                                 int N, int Kreal, int KP) {
  int idx = blockIdx.x * 256 + threadIdx.x;
  if (idx >= N * KP) return;
  int n = idx / KP, k = idx % KP;
  dst[idx] = (k < Kreal) ? f2bf(src[(size_t)n * Kreal + k]) : (u16)0;
}

// ---------------------------------------------------------------- build x0 (bf16, ld 416, pad pre-zeroed)
__global__ void build_x0_kernel(const float* __restrict__ ent_emb, const float* __restrict__ rel_emb,
                                const float* __restrict__ pos_emb, const int* __restrict__ rel_idx,
                                const int* __restrict__ ent_idx, u16* __restrict__ x0) {
  int idx = blockIdx.x * 256 + threadIdx.x;
  if (idx >= 512 * 4 * 400) return;
  int d = idx % 400;
  int l = (idx / 400) % 4;
  int b = idx / 1600;
  float v;
  if (l == 0) v = rel_emb[(size_t)rel_idx[b] * 400 + d];
  else        v = ent_emb[(size_t)ent_idx[b * 3 + l - 1] * 400 + d];
  x0[(size_t)(b * 4 + l) * 416 + d] = f2bf(v + pos_emb[l * 400 + d]);
}

// ---------------------------------------------------------------- MFMA GEMM, 128x128 tile, Ktile 32
// C[m,n] = sum_k A[m,k] * B[n,k] + bias[n].  A bf16 (lda elems, K padded to KP, pad cols zero).
// B: BF32 ? fp32 (ldb = Kreal row stride, zero-fill k>=Kreal) : bf16 (ldb = KP, pre-padded).
// M % 128 == 0; N arbitrary (row-clamped staging + guarded stores).
template<bool BF32, bool RELU, bool OUTBF>
__global__ __launch_bounds__(256) void mfma_gemm(
    const u16* __restrict__ A, int lda,
    const void* __restrict__ Bp, int ldb,
    const float* __restrict__ bias,
    void* __restrict__ Cp, long long ldc,
    int N, int KP, int Kreal) {
  __shared__ u16 As[128 * 32];
  __shared__ u16 Bs[128 * 32];
  const int m0 = blockIdx.x * 128, n0 = blockIdx.y * 128;
  const int tid = threadIdx.x;
  const int lane = tid & 63, w = tid >> 6;
  const int mw = (w & 1) * 64, nw = (w >> 1) * 64;
  f4v acc[4][4] = {};

  // staging map: flat16 = t*256 + tid -> row = t*64 + (tid>>2), 8 elems at (tid&3)*8
  const int arow = tid >> 2, akq = tid & 3;
  const u16* ag0 = A + (size_t)(m0 + arow) * lda + akq * 8;
  const u16* ag1 = A + (size_t)(m0 + 64 + arow) * lda + akq * 8;
  int br0 = n0 + arow;      if (br0 >= N) br0 = N - 1;
  int br1 = n0 + 64 + arow; if (br1 >= N) br1 = N - 1;
  const u16* bg0 = nullptr; const u16* bg1 = nullptr;
  if (!BF32) {
    bg0 = (const u16*)Bp + (size_t)br0 * ldb + akq * 8;
    bg1 = (const u16*)Bp + (size_t)br1 * ldb + akq * 8;
  }
  const float* Bf = (const float*)Bp;

  u16* lA0 = As + w * 512;          // + lane*8 implicit (HW: uniform base + lane*16B)
  u16* lA1 = As + 2048 + w * 512;
  u16* lB0 = Bs + w * 512;
  u16* lB1 = Bs + 2048 + w * 512;

  const u16* ap = As + (size_t)(mw + (lane & 15)) * 32 + (lane >> 4) * 8;
  const u16* bp = Bs + (size_t)(nw + (lane & 15)) * 32 + (lane >> 4) * 8;

  for (int k0 = 0; k0 < KP; k0 += 32) {
    __builtin_amdgcn_global_load_lds((gas_u32*)(ag0 + k0), (las_u32*)lA0, 16, 0, 0);
    __builtin_amdgcn_global_load_lds((gas_u32*)(ag1 + k0), (las_u32*)lA1, 16, 0, 0);
    if (BF32) {
      int kk = k0 + akq * 8;
#pragma unroll
      for (int t = 0; t < 2; ++t) {
        int rowg = t ? br1 : br0;
        const float* src = Bf + (size_t)rowg * ldb + kk;
        float4 v0 = (kk < Kreal)     ? *(const float4*)(src)     : make_float4(0.f, 0.f, 0.f, 0.f);
        float4 v1 = (kk + 4 < Kreal) ? *(const float4*)(src + 4) : make_float4(0.f, 0.f, 0.f, 0.f);
        u32x4 pk;
        pk.x = (unsigned)f2bf(v0.x) | ((unsigned)f2bf(v0.y) << 16);
        pk.y = (unsigned)f2bf(v0.z) | ((unsigned)f2bf(v0.w) << 16);
        pk.z = (unsigned)f2bf(v1.x) | ((unsigned)f2bf(v1.y) << 16);
        pk.w = (unsigned)f2bf(v1.z) | ((unsigned)f2bf(v1.w) << 16);
        *(u32x4*)(Bs + t * 2048 + tid * 8) = pk;
      }
    } else {
      __builtin_amdgcn_global_load_lds((gas_u32*)(bg0 + k0), (las_u32*)lB0, 16, 0, 0);
      __builtin_amdgcn_global_load_lds((gas_u32*)(bg1 + k0), (las_u32*)lB1, 16, 0, 0);
    }
    __syncthreads();
    s8v af[4], bf[4];
#pragma unroll
    for (int i = 0; i < 4; ++i) af[i] = *(const s8v*)(ap + i * 16 * 32);
#pragma unroll
    for (int j = 0; j < 4; ++j) bf[j] = *(const s8v*)(bp + j * 16 * 32);
#pragma unroll
    for (int i = 0; i < 4; ++i)
#pragma unroll
      for (int j = 0; j < 4; ++j)
        acc[i][j] = __builtin_amdgcn_mfma_f32_16x16x32_bf16(af[i], bf[j], acc[i][j], 0, 0, 0);
    __syncthreads();
  }

  const int quad = lane >> 4, col = lane & 15;
#pragma unroll
  for (int i = 0; i < 4; ++i) {
#pragma unroll
    for (int j = 0; j < 4; ++j) {
      int n = n0 + nw + 16 * j + col;
      if (n >= N) continue;
      float bv = bias[n];
#pragma unroll
      for (int r = 0; r < 4; ++r) {
        int m = m0 + mw + 16 * i + quad * 4 + r;
        float v = acc[i][j][r] + bv;
        if (RELU) v = fmaxf(v, 0.f);
        size_t off = (size_t)m * ldc + n;
        if (OUTBF) ((u16*)Cp)[off] = f2bf(v);
        else       ((float*)Cp)[off] = v;
      }
    }
  }
}

// ---------------------------------------------------------------- small VALU gemm (fp32 W from d_in)
__global__ __launch_bounds__(256) void sgemm_valu(
    const u16* __restrict__ X, int lda,
    const float* __restrict__ W, const float* __restrict__ bvec,
    float* __restrict__ Y, int ldc, int M, int N, int K) {
  int n0 = blockIdx.x * 64, m0 = blockIdx.y * 64;
  __shared__ float Xs[16][64];
  __shared__ float Ws[16][64];
  int tid = threadIdx.x;
  int tx = tid & 15, ty = tid >> 4;
  int lr = tid >> 2, lc = (tid & 3) << 2;
  float acc[4][4] = {};
  const u16* xbase = X + (size_t)(m0 + lr) * lda + lc;
  int wn = n0 + lr;
  bool wvalid = wn < N;
  const float* wbase = W + (size_t)(wvalid ? wn : 0) * K + lc;
  for (int k0 = 0; k0 < K; k0 += 16) {
#pragma unroll
    for (int j = 0; j < 4; ++j) Xs[lc + j][lr] = bf2f(xbase[k0 + j]);
#pragma unroll
    for (int j = 0; j < 4; ++j) Ws[lc + j][lr] = wvalid ? wbase[k0 + j] : 0.f;
    __syncthreads();
#pragma unroll
    for (int kk = 0; kk < 16; ++kk) {
      float xv[4], wv[4];
#pragma unroll
      for (int a = 0; a < 4; ++a) xv[a] = Xs[kk][ty * 4 + a];
#pragma unroll
      for (int b = 0; b < 4; ++b) wv[b] = Ws[kk][tx * 4 + b];
#pragma unroll
      for (int a = 0; a < 4; ++a)
#pragma unroll
        for (int b = 0; b < 4; ++b)
          acc[a][b] = fmaf(xv[a], wv[b], acc[a][b]);
    }
    __syncthreads();
  }
#pragma unroll
  for (int a = 0; a < 4; ++a) {
    int m = m0 + ty * 4 + a;
#pragma unroll
    for (int b = 0; b < 4; ++b) {
      int n = n0 + tx * 4 + b;
      if (n < N) Y[(size_t)m * ldc + n] = acc[a][b] + bvec[n];
    }
  }
}

// ---------------------------------------------------------------- attention
__device__ __forceinline__ float wave_sum(float v) {
#pragma unroll
  for (int o = 32; o > 0; o >>= 1) v += __shfl_xor(v, o);
  return v;
}

__global__ void score_kernel(const u16* __restrict__ qkv, float* __restrict__ att) {
  int bh = blockIdx.x;            // b*4 + h
  int h = bh & 3, b = bh >> 2;
  int lane = threadIdx.x;
  float s[4][4];
#pragma unroll
  for (int l = 0; l < 4; ++l) {
    const u16* qp = qkv + (size_t)(b * 4 + l) * 4800 + h * 400;
#pragma unroll
    for (int m = 0; m < 4; ++m) {
      const u16* kp = qkv + (size_t)(b * 4 + m) * 4800 + 1600 + h * 400;
      float p = 0.f;
      for (int d = lane; d < 400; d += 64) p += bf2f(qp[d]) * bf2f(kp[d]);
      s[l][m] = wave_sum(p) * 0.05f;   // 1/sqrt(400)
    }
  }
  if (lane < 16) {
    int l = lane >> 2, m = lane & 3;
    float mx = fmaxf(fmaxf(s[l][0], s[l][1]), fmaxf(s[l][2], s[l][3]));
    float e0 = expf(s[l][0] - mx), e1 = expf(s[l][1] - mx);
    float e2 = expf(s[l][2] - mx), e3 = expf(s[l][3] - mx);
    float inv = 1.f / (e0 + e1 + e2 + e3);
    float ev = (m == 0) ? e0 : (m == 1) ? e1 : (m == 2) ? e2 : e3;
    att[(size_t)bh * 16 + l * 4 + m] = ev * inv;
  }
}

// o[b,l,h,d] = sum_m att[b,h,l,m] * v[b,m,h,d]; v at qkv col offset 3200
__global__ void attn_apply_kernel(const float* __restrict__ att, const u16* __restrict__ qkv,
                                  u16* __restrict__ o) {
  int idx = blockIdx.x * 256 + threadIdx.x;
  if (idx >= 2048 * 1600) return;
  int col = idx % 1600;       // h*400 + d
  int row = idx / 1600;       // b*4 + l
  int b = row >> 2, l = row & 3, h = col / 400;
  const float* ap = att + ((size_t)b * 4 + h) * 16 + l * 4;
  float acc = 0.f;
#pragma unroll
  for (int m = 0; m < 4; ++m)
    acc += ap[m] * bf2f(qkv[(size_t)(b * 4 + m) * 4800 + 3200 + col]);
  o[idx] = f2bf(acc);
}

// ---------------------------------------------------------------- rowwise LN(A_bf16 + Bv_f32), len 400
__global__ __launch_bounds__(128) void ln_kernel(const u16* __restrict__ A, int lda,
                                                 const float* __restrict__ Bv, int ldb,
                                                 const float* __restrict__ g, const float* __restrict__ beta,
                                                 u16* __restrict__ out, int ldo) {
  int row = blockIdx.x;
  int tid = threadIdx.x;
  const u16* a = A + (size_t)row * lda;
  const float* bb = Bv + (size_t)row * ldb;
  float vals[4] = {};
  float s = 0.f, q = 0.f;
#pragma unroll
  for (int j = 0; j < 4; ++j) {
    int d = tid + j * 128;
    if (d < 400) { float x = bf2f(a[d]) + bb[d]; vals[j] = x; s += x; q += x * x; }
  }
  __shared__ float rs[128], rq[128];
  rs[tid] = s; rq[tid] = q;
  __syncthreads();
  for (int off = 64; off > 0; off >>= 1) {
    if (tid < off) { rs[tid] += rs[tid + off]; rq[tid] += rq[tid + off]; }
    __syncthreads();
  }
  float mean = rs[0] * (1.f / 400.f);
  float var = rq[0] * (1.f / 400.f) - mean * mean;
  float rstd = rsqrtf(var + 1e-5f);
  u16* op = out + (size_t)row * ldo;
#pragma unroll
  for (int j = 0; j < 4; ++j) {
    int d = tid + j * 128;
    if (d < 400) op[d] = f2bf((vals[j] - mean) * rstd * g[d] + beta[d]);
  }
}

// ---------------------------------------------------------------- global sum/sumsq partials (atomic)
template<typename T>
__global__ __launch_bounds__(256) void stat_partial(const T* __restrict__ base, long long slice_stride,
                                                    int row_stride, int len, long long total, int nb,
                                                    float* __restrict__ sums) {
  int slice = blockIdx.x / nb, chunk = blockIdx.x % nb;
  const T* p = base + (size_t)slice * slice_stride;
  int tid = threadIdx.x;
  float s = 0.f, q = 0.f;
  long long step = (long long)nb * 256;
  for (long long t = (long long)chunk * 256 + tid; t < total; t += step) {
    int row = (int)(t / len), colx = (int)(t % len);
    float x;
    if (sizeof(T) == 2) x = bf2f(((const u16*)p)[(size_t)row * row_stride + colx]);
    else                x = ((const float*)p)[(size_t)row * row_stride + colx];
    s += x; q += x * x;
  }
  __shared__ float rs[256], rq[256];
  rs[tid] = s; rq[tid] = q;
  __syncthreads();
  for (int off = 128; off > 0; off >>= 1) {
    if (tid < off) { rs[tid] += rs[tid + off]; rq[tid] += rq[tid + off]; }
    __syncthreads();
  }
  if (tid == 0) {
    atomicAdd(&sums[2 * slice], rs[0]);
    atomicAdd(&sums[2 * slice + 1], rq[0]);
  }
}

__device__ __forceinline__ void mean_rstd(const float* sums, float count, float& m, float& rstd) {
  m = sums[0] / count;
  float var = sums[1] / count - m * m;
  rstd = rsqrtf(var + 1e-5f);
}

// ---------------------------------------------------------------- y3[i][b][p*400+d] = f[b,p]*xn(x2[b,i+1,d])
__global__ void build_y3_kernel(const u16* __restrict__ x2, const float* __restrict__ f,
                                const float* __restrict__ scal, const float* __restrict__ pg,
                                const float* __restrict__ pb, u16* __restrict__ y3) {
  int idx = blockIdx.x * 256 + threadIdx.x;
  if (idx >= 3 * 512 * 6400) return;
  int d = idx % 400;
  int p = (idx / 400) % 16;
  int b = (idx / 6400) % 512;
  int i = idx / (512 * 6400);
  float m, rstd;
  mean_rstd(scal + 2 * i, 204800.f, m, rstd);
  float e = bf2f(x2[(size_t)(b * 4 + i + 1) * 400 + d]);
  float xn = (e - m) * rstd * pg[0] + pb[0];
  y3[idx] = f2bf(f[b * 16 + p] * xn);
}

// ---------------------------------------------------------------- conv (bkj,bij->bki) + pairwise maxpool
// efI layout: [arity i][b][d] (rows 1536 x 400).  flat[b][p] = efI[(p/400)*512 + b][p%400]
__global__ void convpool_kernel(const float* __restrict__ kern, const float* __restrict__ efI,
                                const float* __restrict__ scal, const float* __restrict__ bg_,
                                const float* __restrict__ bb_, u16* __restrict__ pooled) {
  int idx = blockIdx.x * 256 + threadIdx.x;
  if (idx >= 512 * 32 * 200) return;
  int i2 = idx % 200;
  int k = (idx / 200) % 32;
  int b = idx / 6400;
  float m, rstd;
  mean_rstd(scal, 614400.f, m, rstd);
  float bg = bg_[0], bb = bb_[0];
  const float* kp = kern + (size_t)b * 96 + k * 3;
  float c0 = 0.f, c1 = 0.f;
#pragma unroll
  for (int j = 0; j < 3; ++j) {
    int p0 = 6 * i2 + j;
    int p1 = 6 * i2 + 3 + j;
    float e0 = efI[(size_t)(p0 / 400) * 204800 + (size_t)b * 400 + (p0 % 400)];
    float e1 = efI[(size_t)(p1 / 400) * 204800 + (size_t)b * 400 + (p1 % 400)];
    c0 += kp[j] * ((e0 - m) * rstd * bg + bb);
    c1 += kp[j] * ((e1 - m) * rstd * bg + bb);
  }
  pooled[(size_t)b * 6400 + k * 200 + i2] = f2bf(fmaxf(c0, c1));
}

// ---------------------------------------------------------------- launch
extern "C" void kernel_launch(void* const* d_in, const int* in_sizes, int n_in,
                              void* d_out, int out_size, void* d_ws, size_t ws_size,
                              hipStream_t stream) {
  const float* ent_emb    = (const float*)d_in[0];
  const float* rel_emb    = (const float*)d_in[1];
  const float* pos_emb    = (const float*)d_in[2];
  const float* relposw_w  = (const float*)d_in[3];
  const float* relposw_b  = (const float*)d_in[4];
  const float* relposinv_w= (const float*)d_in[5];
  const float* relposinv_b= (const float*)d_in[6];
  const float* relw4_w    = (const float*)d_in[7];
  const float* relw4_b    = (const float*)d_in[8];
  const float* q_w        = (const float*)d_in[9];
  const float* q_b        = (const float*)d_in[10];
  const float* k_w        = (const float*)d_in[11];
  const float* k_b        = (const float*)d_in[12];
  const float* v_w        = (const float*)d_in[13];
  const float* v_b        = (const float*)d_in[14];
  const float* fca_w      = (const float*)d_in[15];
  const float* fca_b      = (const float*)d_in[16];
  const float* ln1_g      = (const float*)d_in[17];
  const float* ln1_b      = (const float*)d_in[18];
  const float* ln2_g      = (const float*)d_in[19];
  const float* ln2_b      = (const float*)d_in[20];
  const float* w1_w       = (const float*)d_in[21];
  const float* w1_b       = (const float*)d_in[22];
  const float* w2_w       = (const float*)d_in[23];
  const float* w2_b       = (const float*)d_in[24];
  const float* fc_w       = (const float*)d_in[25];
  const float* fc_b       = (const float*)d_in[26];
  const float* posbn_g    = (const float*)d_in[27];
  const float* posbn_b    = (const float*)d_in[28];
  const float* bn_g       = (const float*)d_in[29];
  const float* bn_b       = (const float*)d_in[30];
  const float* bias       = (const float*)d_in[31];
  const int*  rel_idx     = (const int*)d_in[32];
  const int*  ent_idx     = (const int*)d_in[33];

  char* base = (char*)d_ws;
  // ---- persistent arena (57.9 MB total) ----
  u16*   wqkv  = (u16*)(base + 0);          // 4800x416 bf16
  u16*   wfca  = (u16*)(base + 3993600);    // 400x1600
  u16*   ww1   = (u16*)(base + 5273600);    // 800x416
  u16*   ww2   = (u16*)(base + 5939200);    // 400x800
  u16*   wrpi  = (u16*)(base + 6579200);    // 400x6400
  u16*   wfc   = (u16*)(base + 11699200);   // 400x6400
  float* qkvb  = (float*)(base + 16819200); // 4800 f32 (concat q_b|k_b|v_b)
  u16*   x0    = (u16*)(base + 16838400);   // 2048x416
  u16*   x1    = (u16*)(base + 18542336);   // 2048x416
  u16*   hbuf  = (u16*)(base + 20246272);   // 512x416
  float* att   = (float*)(base + 20672256); // 512x4x16
  float* tmp32 = (float*)(base + 20803328); // 2048x400 f32 (fca out, then w2 out)
  u16*   x2    = (u16*)(base + 24080128);   // 2048x400
  float* fbuf  = (float*)(base + 25718528); // 512x16
  float* kern  = (float*)(base + 25751296); // 512x96
  float* efI   = (float*)(base + 25947904); // 1536x400 f32
  float* scal  = (float*)(base + 28405504); // 16 f32 (sum/sumsq pairs)
  u16*   qkvbuf= (u16*)(base + 28405760);   // 2048x4800 (alias: y3 1536x6400)
  u16*   y3    = qkvbuf;
  u16*   obuf  = (u16*)(base + 48066560);   // 2048x1600 (alias: pooled 512x6400)
  u16*   pooled= obuf;
  u16*   ffn1  = (u16*)(base + 54620160);   // 2048x800

  dim3 blk(256);

  // zero padded activation buffers (x0|x1|hbuf contiguous) + stat accumulators
  hipMemsetAsync(base + 16838400, 0, 3833856, stream);
  hipMemsetAsync(scal, 0, 64, stream);

  // concat qkv bias
  hipMemcpyAsync(qkvb,        q_b, 1600 * 4, hipMemcpyDeviceToDevice, stream);
  hipMemcpyAsync(qkvb + 1600, k_b, 1600 * 4, hipMemcpyDeviceToDevice, stream);
  hipMemcpyAsync(qkvb + 3200, v_b, 1600 * 4, hipMemcpyDeviceToDevice, stream);

  // weight conversions (fp32 -> bf16, K-padded)
  convert_w_kernel<<<(1600 * 416 + 255) / 256, blk, 0, stream>>>(q_w, wqkv,              1600, 400, 416);
  convert_w_kernel<<<(1600 * 416 + 255) / 256, blk, 0, stream>>>(k_w, wqkv + 1600 * 416, 1600, 400, 416);
  convert_w_kernel<<<(1600 * 416 + 255) / 256, blk, 0, stream>>>(v_w, wqkv + 3200 * 416, 1600, 400, 416);
  convert_w_kernel<<<(400 * 1600 + 255) / 256, blk, 0, stream>>>(fca_w, wfca, 400, 1600, 1600);
  convert_w_kernel<<<(800 * 416 + 255) / 256,  blk, 0, stream>>>(w1_w, ww1, 800, 400, 416);
  convert_w_kernel<<<(400 * 800 + 255) / 256,  blk, 0, stream>>>(w2_w, ww2, 400, 800, 800);
  convert_w_kernel<<<(400 * 6400 + 255) / 256, blk, 0, stream>>>(relposinv_w, wrpi, 400, 6400, 6400);
  convert_w_kernel<<<(400 * 6400 + 255) / 256, blk, 0, stream>>>(fc_w, wfc, 400, 6400, 6400);

  // x0 = gather + pos
  build_x0_kernel<<<3200, blk, 0, stream>>>(ent_emb, rel_emb, pos_emb, rel_idx, ent_idx, x0);

  // fused qkv: (2048,416) @ (4800,416)^T -> qkvbuf bf16
  mfma_gemm<false, false, true><<<dim3(16, 38), blk, 0, stream>>>(
      x0, 416, wqkv, 416, qkvb, qkvbuf, 4800, 4800, 416, 416);

  score_kernel<<<2048, 64, 0, stream>>>(qkvbuf, att);
  attn_apply_kernel<<<12800, blk, 0, stream>>>(att, qkvbuf, obuf);

  // fca: o(2048,1600) @ (400,1600)^T -> tmp32
  mfma_gemm<false, false, false><<<dim3(16, 4), blk, 0, stream>>>(
      obuf, 1600, wfca, 1600, fca_b, tmp32, 400, 400, 1600, 1600);
  ln_kernel<<<2048, 128, 0, stream>>>(x0, 416, tmp32, 400, ln1_g, ln1_b, x1, 416);

  // FFN
  mfma_gemm<false, true, true><<<dim3(16, 7), blk, 0, stream>>>(
      x1, 416, ww1, 416, w1_b, ffn1, 800, 800, 416, 416);
  mfma_gemm<false, false, false><<<dim3(16, 4), blk, 0, stream>>>(
      ffn1, 800, ww2, 800, w2_b, tmp32, 400, 400, 800, 800);
  ln_kernel<<<2048, 128, 0, stream>>>(x1, 416, tmp32, 400, ln2_g, ln2_b, x2, 400);

  // f = r @ relposw^T ; kern = r @ relw4^T   (r = x2[:,0,:], row stride 1600)
  sgemm_valu<<<dim3(1, 8), blk, 0, stream>>>(x2, 1600, relposw_w, relposw_b, fbuf, 16, 512, 16, 400);
  sgemm_valu<<<dim3(2, 8), blk, 0, stream>>>(x2, 1600, relw4_w, relw4_b, kern, 96, 512, 96, 400);

  // global stats of x2[:, i+1, :] (3 slices) -> scal[0..5] (sum/sumsq)
  stat_partial<u16><<<3 * 16, blk, 0, stream>>>(x2 + 400, 400, 1600, 400, 204800, 16, scal);

  // y3 = f ⊗ xn (3 slices batched), then ef = y3 @ relposinv^T (M=1536)
  build_y3_kernel<<<38400, blk, 0, stream>>>(x2, fbuf, scal, posbn_g, posbn_b, y3);
  mfma_gemm<false, false, false><<<dim3(12, 4), blk, 0, stream>>>(
      y3, 6400, wrpi, 6400, relposinv_b, efI, 400, 400, 6400, 6400);

  // global stats of ef -> scal[6..7]
  stat_partial<float><<<32, blk, 0, stream>>>(efI, 0, 400, 400, 614400, 32, scal + 6);

  // conv + maxpool -> pooled bf16
  convpool_kernel<<<12800, blk, 0, stream>>>(kern, efI, scal + 6, bn_g, bn_b, pooled);

  // h = relu(pooled @ fc^T) -> hbuf (bf16, ld 416, pad pre-zeroed)
  mfma_gemm<false, true, true><<<dim3(4, 4), blk, 0, stream>>>(
      pooled, 6400, wfc, 6400, fc_b, hbuf, 416, 400, 6400, 6400);

  // out = h @ ent_emb^T + bias  (M=512, N=200000, fp32 B staged+converted in-kernel)
  mfma_gemm<true, false, false><<<dim3(4, 1563), blk, 0, stream>>>(
      hbuf, 416, ent_emb, 400, bias, d_out, 200000, 200000, 416, 400);
}